// Round 15
// baseline (33.151 us; speedup 1.0000x reference)
//
#include <hip/hip_runtime.h>
#include <math.h>

#define NQ 6
#define NLAYERS 3
#define QBATCH 262144
#define UPITCH 66          // fp16 elems per U_T row (64 + 2 pad: bank spread)

typedef float  f2   __attribute__((ext_vector_type(2)));
typedef float  f4v  __attribute__((ext_vector_type(4)));
typedef float  f16f __attribute__((ext_vector_type(16)));
typedef __fp16 h2v  __attribute__((ext_vector_type(2)));
typedef __fp16 h8v  __attribute__((ext_vector_type(8)));

template<int C>
__device__ __forceinline__ float dppf(float v) {
    return __int_as_float(__builtin_amdgcn_update_dpp(
        0, __float_as_int(v), C, 0xF, 0xF, true));
}
template<int C>
__device__ __forceinline__ f2 dpp2(f2 v) {
    f2 r; r.x = dppf<C>(v.x); r.y = dppf<C>(v.y); return r;
}
// DPP quad_perm ctrls: 0xB1 = lane^1, 0x4E = lane^2, 0xB4 = swap lanes {2,3}
__device__ __forceinline__ float tanh_fast(float a) {
    const float e = __expf(2.f * a);
    return 1.f - 2.f * __builtin_amdgcn_rcpf(e + 1.f);
}
__device__ __forceinline__ f2 sp(float v) { f2 r; r.x = v; r.y = v; return r; }

// fused-gate (RZ*RY*RX) coefficients, computed inline in registers from qw.
// Same math as the verified phase A; __sinf/__cosf (~1e-6 err << fp16 U).
__device__ __forceinline__ void gate_coeffs(const float* __restrict__ qw, int g,
    float& g00r, float& g00i, float& g01r, float& g01i,
    float& g10r, float& g10i, float& g11r, float& g11i)
{
    const float t0 = qw[g*3+0] * 0.5f;
    const float t1 = qw[g*3+1] * 0.5f;
    const float t2 = qw[g*3+2] * 0.5f;
    const float s0 = __sinf(t0), c0 = __cosf(t0);
    const float s1 = __sinf(t1), c1 = __cosf(t1);
    const float s2 = __sinf(t2), c2 = __cosf(t2);
    const float m00r =  c1*c0, m00i =  s1*s0;
    const float m01r = -s1*c0, m01i = -c1*s0;
    const float m10r =  s1*c0, m10i = -c1*s0;
    const float m11r =  c1*c0, m11i = -s1*s0;
    g00r = c2*m00r + s2*m00i; g00i = c2*m00i - s2*m00r;
    g01r = c2*m01r + s2*m01i; g01i = c2*m01i - s2*m01r;
    g10r = c2*m10r - s2*m10i; g10i = c2*m10i + s2*m10r;
    g11r = c2*m11r - s2*m11i; g11i = c2*m11i + s2*m11r;
}

// ===========================================================================
// Fused v3 — ONE launch, no d_ws, no cross-block dependency.
// R11/R12 fused failures diagnosed: (a) per-gate LDS coefficient reads put
// ~324 ds_reads on the sim critical path; (b) combined unrolled code > I$.
// Fix: coefficients inline in REGISTERS from qw (wave-uniform s_loads, zero
// LDS latency), rolled layer + rolled T loops keep code ~13KB. Each block:
// sim (4 lanes/basis col) -> U_T fp16 in LDS -> frag build -> R14 main on
// 256 samples. LDS 34.5KB -> 4 blocks/CU.
// ===========================================================================
__global__ __launch_bounds__(256) void qnn_all(
    const float* __restrict__ x,
    const float* __restrict__ pre_w1, const float* __restrict__ pre_b1,
    const float* __restrict__ pre_w2, const float* __restrict__ pre_b2,
    const float* __restrict__ qw,
    const float* __restrict__ post_w1, const float* __restrict__ post_b1,
    const float* __restrict__ post_w2, const float* __restrict__ post_b2,
    float* __restrict__ out)
{
    __shared__ __align__(16) __fp16 shbuf[2 * 64 * UPITCH];  // uh, then ps
    __shared__ __align__(16) __fp16 w1s[9216];               // 18KB frags
    __fp16* UhreT = shbuf;
    __fp16* UhimT = shbuf + 64 * UPITCH;
    const int tid  = threadIdx.x;
    const int lane = tid & 63, wid = tid >> 6;

    // --- sim: quad (tid>>2) = basis column; lane bit0 = qubit5, bit1 = qubit4
    {
        const int p5 = tid & 1, p4 = (tid >> 1) & 1, bt = tid >> 2;
        f2 R[8], U[8];
        #pragma unroll
        for (int j = 0; j < 8; ++j) {
            const bool own = (((bt >> 1) & 7) == j) &&
                             (((bt >> 4) & 1) == p4) && (((bt >> 5) & 1) == p5);
            R[j].x = (own && (bt & 1) == 0) ? 1.f : 0.f;
            R[j].y = (own && (bt & 1) == 1) ? 1.f : 0.f;
            U[j].x = 0.f; U[j].y = 0.f;
        }
        #pragma unroll 1
        for (int l = 0; l < NLAYERS; ++l) {
            // CX chain (verified R12 pattern)
            #pragma unroll
            for (int j = 0; j < 8; j += 2) {
                float t;
                t = R[j].y; R[j].y = R[j+1].y; R[j+1].y = t;
                t = U[j].y; U[j].y = U[j+1].y; U[j+1].y = t;
            }
            #pragma unroll
            for (int j = 1; j < 8; j += 4) {
                f2 t;
                t = R[j]; R[j] = R[j+2]; R[j+2] = t;
                t = U[j]; U[j] = U[j+2]; U[j+2] = t;
            }
            #pragma unroll
            for (int j = 2; j < 4; ++j) {
                f2 t;
                t = R[j]; R[j] = R[j+4]; R[j+4] = t;
                t = U[j]; U[j] = U[j+4]; U[j+4] = t;
            }
            #pragma unroll
            for (int j = 4; j < 8; ++j) {
                R[j] = dpp2<0x4E>(R[j]);
                U[j] = dpp2<0x4E>(U[j]);
            }
            #pragma unroll
            for (int j = 0; j < 8; ++j) {
                R[j] = dpp2<0xB4>(R[j]);
                U[j] = dpp2<0xB4>(U[j]);
            }

            // gate q=0: packed in-reg pairs (mixed-row coeffs, broadcasts)
            {
                float g00r,g00i,g01r,g01i,g10r,g10i,g11r,g11i;
                gate_coeffs(qw, l*6+0, g00r,g00i,g01r,g01i,g10r,g10i,g11r,g11i);
                f2 A, Ai, nAi, C, Ci, nCi;
                A.x  = g00r; A.y  = g10r;  Ai.x  = g00i; Ai.y  = g10i;
                nAi.x = -g00i; nAi.y = -g10i;
                C.x  = g01r; C.y  = g11r;  Ci.x  = g01i; Ci.y  = g11i;
                nCi.x = -g01i; nCi.y = -g11i;
                #pragma unroll
                for (int j = 0; j < 8; ++j) {
                    const f2 z = R[j], u = U[j];
                    const f2 br0 = __builtin_shufflevector(z, z, 0, 0);
                    const f2 br1 = __builtin_shufflevector(z, z, 1, 1);
                    const f2 bu0 = __builtin_shufflevector(u, u, 0, 0);
                    const f2 bu1 = __builtin_shufflevector(u, u, 1, 1);
                    R[j] = __builtin_elementwise_fma(nCi, bu1, __builtin_elementwise_fma(C,  br1, __builtin_elementwise_fma(nAi, bu0, A  * br0)));
                    U[j] = __builtin_elementwise_fma(C,   bu1, __builtin_elementwise_fma(Ci, br1, __builtin_elementwise_fma(A,   bu0, Ai * br0)));
                }
            }
            // gates q=1..3: lane-local reg pairs, splat coeffs
            #pragma unroll
            for (int q = 1; q < 4; ++q) {
                float g00r,g00i,g01r,g01i,g10r,g10i,g11r,g11i;
                gate_coeffs(qw, l*6+q, g00r,g00i,g01r,g01i,g10r,g10i,g11r,g11i);
                const f2 a00r = sp(g00r), a00i = sp(g00i), n00i = sp(-g00i);
                const f2 a01r = sp(g01r), a01i = sp(g01i), n01i = sp(-g01i);
                const f2 a10r = sp(g10r), a10i = sp(g10i), n10i = sp(-g10i);
                const f2 a11r = sp(g11r), a11i = sp(g11i), n11i = sp(-g11i);
                const int bit = 1 << (q - 1);
                #pragma unroll
                for (int m = 0; m < 4; ++m) {
                    const int ja = ((m >> (q-1)) << q) | (m & (bit - 1));
                    const int jb = ja | bit;
                    const f2 zr0 = R[ja], zu0 = U[ja];
                    const f2 zr1 = R[jb], zu1 = U[jb];
                    R[ja] = __builtin_elementwise_fma(n01i, zu1, __builtin_elementwise_fma(a01r, zr1, __builtin_elementwise_fma(n00i, zu0, a00r * zr0)));
                    U[ja] = __builtin_elementwise_fma(a01r, zu1, __builtin_elementwise_fma(a01i, zr1, __builtin_elementwise_fma(a00r, zu0, a00i * zr0)));
                    R[jb] = __builtin_elementwise_fma(n11i, zu1, __builtin_elementwise_fma(a11r, zr1, __builtin_elementwise_fma(n10i, zu0, a10r * zr0)));
                    U[jb] = __builtin_elementwise_fma(a11r, zu1, __builtin_elementwise_fma(a11i, zr1, __builtin_elementwise_fma(a10r, zu0, a10i * zr0)));
                }
            }
            // gate q=4: partner = lane^2 (same reg), rows by p4
            {
                float g00r,g00i,g01r,g01i,g10r,g10i,g11r,g11i;
                gate_coeffs(qw, l*6+4, g00r,g00i,g01r,g01i,g10r,g10i,g11r,g11i);
                const bool sw = ((tid >> 1) & 1) != 0;
                const float crr = sw ? g11r : g00r, cri = sw ? g11i : g00i;
                const float cpr = sw ? g10r : g01r, cpi = sw ? g10i : g01i;
                const f2 rrr = sp(crr), rri = sp(cri), nrri = sp(-cri);
                const f2 rpr = sp(cpr), rpi = sp(cpi), nrpi = sp(-cpi);
                #pragma unroll
                for (int j = 0; j < 8; ++j) {
                    const f2 z = R[j], u = U[j];
                    const f2 pr = dpp2<0x4E>(z), pu = dpp2<0x4E>(u);
                    R[j] = __builtin_elementwise_fma(nrpi, pu, __builtin_elementwise_fma(rpr, pr, __builtin_elementwise_fma(nrri, u, rrr * z)));
                    U[j] = __builtin_elementwise_fma(rpr,  pu, __builtin_elementwise_fma(rpi, pr, __builtin_elementwise_fma(rrr,  u, rri * z)));
                }
            }
            // gate q=5: partner = lane^1 (same reg), rows by p5
            {
                float g00r,g00i,g01r,g01i,g10r,g10i,g11r,g11i;
                gate_coeffs(qw, l*6+5, g00r,g00i,g01r,g01i,g10r,g10i,g11r,g11i);
                const bool sw = (tid & 1) != 0;
                const float crr = sw ? g11r : g00r, cri = sw ? g11i : g00i;
                const float cpr = sw ? g10r : g01r, cpi = sw ? g10i : g01i;
                const f2 rrr = sp(crr), rri = sp(cri), nrri = sp(-cri);
                const f2 rpr = sp(cpr), rpi = sp(cpi), nrpi = sp(-cpi);
                #pragma unroll
                for (int j = 0; j < 8; ++j) {
                    const f2 z = R[j], u = U[j];
                    const f2 pr = dpp2<0xB1>(z), pu = dpp2<0xB1>(u);
                    R[j] = __builtin_elementwise_fma(nrpi, pu, __builtin_elementwise_fma(rpr, pr, __builtin_elementwise_fma(nrri, u, rrr * z)));
                    U[j] = __builtin_elementwise_fma(rpr,  pu, __builtin_elementwise_fma(rpi, pr, __builtin_elementwise_fma(rrr,  u, rri * z)));
                }
            }
        }
        const int base = 16 * p4 + 32 * p5;
        #pragma unroll
        for (int j = 0; j < 8; ++j) {
            *(h2v*)(UhreT + bt*UPITCH + base + 2*j) =
                __builtin_amdgcn_cvt_pkrtz(R[j].x, R[j].y);
            *(h2v*)(UhimT + bt*UPITCH + base + 2*j) =
                __builtin_amdgcn_cvt_pkrtz(U[j].x, U[j].y);
        }
    }
    __syncthreads();

    // --- fragment build into w1s (split across 4 waves; verified R12) ---
    {
        const int r32 = lane & 31, khp = lane >> 5;
        for (int i = wid; i < 16; i += 4) {
            const int T = i >> 2, s = i & 3;
            const int row = 32*T + r32, n = row >> 1, c = row & 1;
            const __fp16* src = c ? UhimT : UhreT;
            h8v v;
            #pragma unroll
            for (int e = 0; e < 8; ++e)
                v[e] = src[(khp*8 + 16*s + e) * UPITCH + n];
            *(h8v*)(w1s + i*512 + lane*8) = v;
        }
        if (wid == 1) {
            const int rlow = lane & 15, kg = lane >> 4;
            float cw[6];
            #pragma unroll
            for (int q = 0; q < 6; ++q) cw[q] = post_w1[q*16 + rlow];
            for (int f = 0; f < 2; ++f) {
                h8v v;
                #pragma unroll
                for (int e = 0; e < 8; ++e) {
                    const int k2 = kg*8 + e + 32*f;
                    float sacc = 0.f;
                    #pragma unroll
                    for (int q = 0; q < 6; ++q)
                        sacc += ((k2 >> q) & 1) ? -cw[q] : cw[q];
                    v[e] = (__fp16)sacc;
                }
                *(h8v*)(w1s + 8192 + f*512 + lane*8) = v;
            }
        }
    }
    __syncthreads();   // w1s ready; shbuf may now be reused as p-tiles

    // --- main (R14 verbatim, frags from LDS) ---
    const h8v a2f0 = *(const h8v*)(w1s + 8192 + lane*8);
    const h8v a2f1 = *(const h8v*)(w1s + 8192 + 512 + lane*8);
    const int sbase = (blockIdx.x * 4 + wid) * 64;

    const float4 xv = ((const float4*)x)[sbase + lane];
    float h[16];
    #pragma unroll
    for (int j = 0; j < 16; ++j) {
        float a = pre_b1[j];
        a = fmaf(xv.x, pre_w1[0*16+j], a);
        a = fmaf(xv.y, pre_w1[1*16+j], a);
        a = fmaf(xv.z, pre_w1[2*16+j], a);
        a = fmaf(xv.w, pre_w1[3*16+j], a);
        h[j] = fmaxf(a, 0.f);
    }
    float fc[NQ], fs[NQ];
    #pragma unroll
    for (int q = 0; q < NQ; ++q) {
        float a = pre_b2[q];
        #pragma unroll
        for (int j = 0; j < 16; ++j) a = fmaf(h[j], pre_w2[j*NQ+q], a);
        const float y = 0.5f * tanh_fast(a) + 0.78539816339744831f;
        fc[q] = __cosf(y); fs[q] = __sinf(y);
    }
    const float b2x = post_b2[0], b2y = post_b2[1];
    const float b2z = post_b2[2], b2w = post_b2[3];

    const int sl32 = lane & 31, kh = lane >> 5;
    const int sl16 = lane & 15, g2 = lane >> 4;
    __fp16* myp = shbuf + wid * 2048;
    const int wswz = (sl32 & 7) << 4;

    #pragma unroll
    for (int G2 = 0; G2 < 2; ++G2) {
        const int srcb = (G2 * 32 + sl32) << 2;
        #define BP(v) __int_as_float(__builtin_amdgcn_ds_bpermute(srcb, __float_as_int(v)))
        const float q0c=BP(fc[0]), q0s=BP(fs[0]);
        const float q1c=BP(fc[1]), q1s=BP(fs[1]);
        const float q2c=BP(fc[2]), q2s=BP(fs[2]);
        const float q3c=BP(fc[3]), q3s=BP(fs[3]);
        const float q4c=BP(fc[4]), q4s=BP(fs[4]);
        const float q5c=BP(fc[5]), q5s=BP(fs[5]);
        #undef BP
        const float f3v = kh ? q3s : q3c;
        float t01[4], b8[8];
        t01[0] = q0c*q1c; t01[1] = q0s*q1c; t01[2] = q0c*q1s; t01[3] = q0s*q1s;
        #pragma unroll
        for (int e = 0; e < 8; ++e) b8[e] = t01[e & 3] * ((e & 4) ? q2s : q2c);
        h8v bs[4];
        #pragma unroll
        for (int s = 0; s < 4; ++s) {
            const float pre = f3v * ((s & 1) ? q4s : q4c) * ((s & 2) ? q5s : q5c);
            #pragma unroll
            for (int e2 = 0; e2 < 4; ++e2) {
                const h2v t = __builtin_amdgcn_cvt_pkrtz(b8[2*e2]*pre, b8[2*e2+1]*pre);
                bs[s][2*e2] = t[0]; bs[s][2*e2+1] = t[1];
            }
        }

        // GEMM1, rolled over T: one live accumulator, inline A-frag LDS loads
        #pragma unroll 1
        for (int T = 0; T < 4; ++T) {
            f16f acc = (f16f)(0.f);
            #pragma unroll
            for (int s = 0; s < 4; ++s) {
                const h8v a = *(const h8v*)(w1s + (T*4 + s)*512 + lane*8);
                acc = __builtin_amdgcn_mfma_f32_32x32x16_f16(a, bs[s], acc, 0, 0, 0);
            }
            #pragma unroll
            for (int a = 0; a < 4; ++a) {
                const float p0 = fmaf(acc[4*a+0], acc[4*a+0], acc[4*a+1] * acc[4*a+1]);
                const float p1 = fmaf(acc[4*a+2], acc[4*a+2], acc[4*a+3] * acc[4*a+3]);
                const h2v ph = __builtin_amdgcn_cvt_pkrtz(p0, p1);
                const int boff = (32*T + 8*a + 4*kh) ^ wswz;
                *(h2v*)((char*)myp + sl32*128 + boff) = ph;
            }
        }

        #pragma unroll
        for (int H = 0; H < 2; ++H) {
            const int smp  = H*16 + sl16;
            const int rswz = (smp & 7) << 4;
            const h8v pb0 = *(const h8v*)((const char*)myp + smp*128 + ((16*g2     ) ^ rswz));
            const h8v pb1 = *(const h8v*)((const char*)myp + smp*128 + ((16*g2 + 64) ^ rswz));
            f4v c2 = {0.f, 0.f, 0.f, 0.f};
            c2 = __builtin_amdgcn_mfma_f32_16x16x32_f16(a2f0, pb0, c2, 0, 0, 0);
            c2 = __builtin_amdgcn_mfma_f32_16x16x32_f16(a2f1, pb1, c2, 0, 0, 0);

            const float4 b1v = ((const float4*)post_b1)[g2];
            const float e0  = fmaxf(c2.x + b1v.x, 0.f);
            const float e1  = fmaxf(c2.y + b1v.y, 0.f);
            const float e2_ = fmaxf(c2.z + b1v.z, 0.f);
            const float e3  = fmaxf(c2.w + b1v.w, 0.f);
            const float4 w0 = ((const float4*)post_w2)[4*g2 + 0];
            const float4 w1 = ((const float4*)post_w2)[4*g2 + 1];
            const float4 w2 = ((const float4*)post_w2)[4*g2 + 2];
            const float4 w3 = ((const float4*)post_w2)[4*g2 + 3];
            float ox = fmaf(e0, w0.x, fmaf(e1, w1.x, fmaf(e2_, w2.x, e3 * w3.x)));
            float oy = fmaf(e0, w0.y, fmaf(e1, w1.y, fmaf(e2_, w2.y, e3 * w3.y)));
            float oz = fmaf(e0, w0.z, fmaf(e1, w1.z, fmaf(e2_, w2.z, e3 * w3.z)));
            float ow = fmaf(e0, w0.w, fmaf(e1, w1.w, fmaf(e2_, w2.w, e3 * w3.w)));
            ox += __shfl_xor(ox, 16, 64); ox += __shfl_xor(ox, 32, 64);
            oy += __shfl_xor(oy, 16, 64); oy += __shfl_xor(oy, 32, 64);
            oz += __shfl_xor(oz, 16, 64); oz += __shfl_xor(oz, 32, 64);
            ow += __shfl_xor(ow, 16, 64); ow += __shfl_xor(ow, 32, 64);
            if (lane < 16) {
                float4 r;
                r.x = ox + b2x; r.y = oy + b2y; r.z = oz + b2z; r.w = ow + b2w;
                ((float4*)out)[sbase + G2*32 + H*16 + sl16] = r;
            }
        }
    }
}

extern "C" void kernel_launch(void* const* d_in, const int* in_sizes, int n_in,
                              void* d_out, int out_size, void* d_ws, size_t ws_size,
                              hipStream_t stream) {
    const float* x       = (const float*)d_in[0];
    const float* pre_w1  = (const float*)d_in[1];
    const float* pre_b1  = (const float*)d_in[2];
    const float* pre_w2  = (const float*)d_in[3];
    const float* pre_b2  = (const float*)d_in[4];
    const float* qw      = (const float*)d_in[5];
    const float* post_w1 = (const float*)d_in[6];
    const float* post_b1 = (const float*)d_in[7];
    const float* post_w2 = (const float*)d_in[8];
    const float* post_b2 = (const float*)d_in[9];
    float* out = (float*)d_out;

    qnn_all<<<QBATCH / 256, 256, 0, stream>>>(   // 1024 blocks, one launch
        x, pre_w1, pre_b1, pre_w2, pre_b2, qw,
        post_w1, post_b1, post_w2, post_b2, out);
}

// Round 17
// 22.247 us; speedup vs baseline: 1.4901x; 1.4901x over previous
//
#include <hip/hip_runtime.h>
#include <math.h>

#define NQ 6
#define NLAYERS 3
#define QBATCH 262144
#define NGATES 18
#define GSTRIDE 40
#define UPITCH 66          // fp16 elems per U_T row (64 + 2 pad: bank spread)

typedef float  f2   __attribute__((ext_vector_type(2)));
typedef float  f4v  __attribute__((ext_vector_type(4)));
typedef float  f16f __attribute__((ext_vector_type(16)));
typedef __fp16 h2v  __attribute__((ext_vector_type(2)));
typedef __fp16 h8v  __attribute__((ext_vector_type(8)));

template<int C>
__device__ __forceinline__ float dppf(float v) {
    return __int_as_float(__builtin_amdgcn_update_dpp(
        0, __float_as_int(v), C, 0xF, 0xF, true));
}
template<int C>
__device__ __forceinline__ f2 dpp2(f2 v) {
    f2 r; r.x = dppf<C>(v.x); r.y = dppf<C>(v.y); return r;
}
// DPP quad_perm ctrls: 0xB1 = lane^1, 0x4E = lane^2, 0xB4 = swap lanes {2,3}
__device__ __forceinline__ float tanh_fast(float a) {
    const float e = __expf(2.f * a);
    return 1.f - 2.f * __builtin_amdgcn_rcpf(e + 1.f);
}

// ===========================================================================
// PREP (1 block, 256 threads) — verified R13/R14 (absmax 1.953e-3).
// Sim: 4 lanes per basis column; U stored transposed fp16 in LDS; fragment
// build split across 4 waves. Output:
//   [0,16KB): GEMM1 A-frags (32x32x16): frag i=(T*4+s), lane l, elem e ->
//             A[row=32T+(l&31)][k=(l>>5)*8+16s+e], row 2n+c = Re/Im U[n][.]
//   [16KB,18KB): GEMM2 A-frags (16x16x32): SW[k2][j]=sum_q SIGNS[k2][q]w1[q][j]
// ===========================================================================
__global__ __launch_bounds__(256) void prep_kernel(
    const float* __restrict__ qw,
    const float* __restrict__ post_w1,
    __fp16* __restrict__ wfrag)
{
    __shared__ f2 gs2[NGATES * GSTRIDE / 2];
    __shared__ __align__(16) __fp16 uh[2 * 64 * UPITCH];
    __fp16* UhreT = uh;
    __fp16* UhimT = uh + 64 * UPITCH;
    const int tid  = threadIdx.x;
    const int lane = tid & 63, wid = tid >> 6;

    if (tid < NGATES) {
        const int pp = tid * 3;
        float s0 = sinf(qw[pp+0]*0.5f), c0 = cosf(qw[pp+0]*0.5f);
        float s1 = sinf(qw[pp+1]*0.5f), c1 = cosf(qw[pp+1]*0.5f);
        float s2 = sinf(qw[pp+2]*0.5f), c2 = cosf(qw[pp+2]*0.5f);
        const float m00r =  c1*c0, m00i =  s1*s0;
        const float m01r = -s1*c0, m01i = -c1*s0;
        const float m10r =  s1*c0, m10i = -c1*s0;
        const float m11r =  c1*c0, m11i = -s1*s0;
        const float g00r = c2*m00r + s2*m00i, g00i = c2*m00i - s2*m00r;
        const float g01r = c2*m01r + s2*m01i, g01i = c2*m01i - s2*m01r;
        const float g10r = c2*m10r - s2*m10i, g10i = c2*m10i + s2*m10r;
        const float g11r = c2*m11r - s2*m11i, g11i = c2*m11i + s2*m11r;
        float* o = (float*)gs2 + tid * GSTRIDE;
        o[0]=o[1]=g00r;  o[2]=o[3]=g00i;  o[4]=o[5]=-g00i;
        o[6]=o[7]=g01r;  o[8]=o[9]=g01i;  o[10]=o[11]=-g01i;
        o[12]=o[13]=g10r; o[14]=o[15]=g10i; o[16]=o[17]=-g10i;
        o[18]=o[19]=g11r; o[20]=o[21]=g11i; o[22]=o[23]=-g11i;
        o[24]=g00r; o[25]=g10r;  o[26]=g00i; o[27]=g10i;
        o[28]=-g00i; o[29]=-g10i; o[30]=g01r; o[31]=g11r;
        o[32]=g01i; o[33]=g11i;  o[34]=-g01i; o[35]=-g11i;
        o[36]=o[37]=o[38]=o[39]=0.f;
    }
    __syncthreads();

    {
        const int p5 = tid & 1, p4 = (tid >> 1) & 1, bt = tid >> 2;
        f2 R[8], U[8];
        #pragma unroll
        for (int j = 0; j < 8; ++j) {
            const bool own = (((bt >> 1) & 7) == j) &&
                             (((bt >> 4) & 1) == p4) && (((bt >> 5) & 1) == p5);
            R[j].x = (own && (bt & 1) == 0) ? 1.f : 0.f;
            R[j].y = (own && (bt & 1) == 1) ? 1.f : 0.f;
            U[j].x = 0.f; U[j].y = 0.f;
        }
        #pragma unroll 1
        for (int l = 0; l < NLAYERS; ++l) {
            #pragma unroll
            for (int j = 0; j < 8; j += 2) {
                float t;
                t = R[j].y; R[j].y = R[j+1].y; R[j+1].y = t;
                t = U[j].y; U[j].y = U[j+1].y; U[j+1].y = t;
            }
            #pragma unroll
            for (int j = 1; j < 8; j += 4) {
                f2 t;
                t = R[j]; R[j] = R[j+2]; R[j+2] = t;
                t = U[j]; U[j] = U[j+2]; U[j+2] = t;
            }
            #pragma unroll
            for (int j = 2; j < 4; ++j) {
                f2 t;
                t = R[j]; R[j] = R[j+4]; R[j+4] = t;
                t = U[j]; U[j] = U[j+4]; U[j+4] = t;
            }
            #pragma unroll
            for (int j = 4; j < 8; ++j) {
                R[j] = dpp2<0x4E>(R[j]);
                U[j] = dpp2<0x4E>(U[j]);
            }
            #pragma unroll
            for (int j = 0; j < 8; ++j) {
                R[j] = dpp2<0xB4>(R[j]);
                U[j] = dpp2<0xB4>(U[j]);
            }

            const f2* lg = gs2 + l * (NQ * (GSTRIDE / 2));
            {
                const f2* gb = lg;
                const f2 A = gb[12], Ai = gb[13], nAi = gb[14];
                const f2 C = gb[15], Ci = gb[16], nCi = gb[17];
                #pragma unroll
                for (int j = 0; j < 8; ++j) {
                    const f2 z = R[j], u = U[j];
                    const f2 br0 = __builtin_shufflevector(z, z, 0, 0);
                    const f2 br1 = __builtin_shufflevector(z, z, 1, 1);
                    const f2 bu0 = __builtin_shufflevector(u, u, 0, 0);
                    const f2 bu1 = __builtin_shufflevector(u, u, 1, 1);
                    R[j] = __builtin_elementwise_fma(nCi, bu1, __builtin_elementwise_fma(C,  br1, __builtin_elementwise_fma(nAi, bu0, A  * br0)));
                    U[j] = __builtin_elementwise_fma(C,   bu1, __builtin_elementwise_fma(Ci, br1, __builtin_elementwise_fma(A,   bu0, Ai * br0)));
                }
            }
            #pragma unroll
            for (int q = 1; q < 4; ++q) {
                const f2* gb = lg + q * (GSTRIDE / 2);
                const f2 a00r = gb[0], a00i = gb[1],  n00i = gb[2];
                const f2 a01r = gb[3], a01i = gb[4],  n01i = gb[5];
                const f2 a10r = gb[6], a10i = gb[7],  n10i = gb[8];
                const f2 a11r = gb[9], a11i = gb[10], n11i = gb[11];
                const int bit = 1 << (q - 1);
                #pragma unroll
                for (int m = 0; m < 4; ++m) {
                    const int ja = ((m >> (q-1)) << q) | (m & (bit - 1));
                    const int jb = ja | bit;
                    const f2 zr0 = R[ja], zu0 = U[ja];
                    const f2 zr1 = R[jb], zu1 = U[jb];
                    R[ja] = __builtin_elementwise_fma(n01i, zu1, __builtin_elementwise_fma(a01r, zr1, __builtin_elementwise_fma(n00i, zu0, a00r * zr0)));
                    U[ja] = __builtin_elementwise_fma(a01r, zu1, __builtin_elementwise_fma(a01i, zr1, __builtin_elementwise_fma(a00r, zu0, a00i * zr0)));
                    R[jb] = __builtin_elementwise_fma(n11i, zu1, __builtin_elementwise_fma(a11r, zr1, __builtin_elementwise_fma(n10i, zu0, a10r * zr0)));
                    U[jb] = __builtin_elementwise_fma(a11r, zu1, __builtin_elementwise_fma(a11i, zr1, __builtin_elementwise_fma(a10r, zu0, a10i * zr0)));
                }
            }
            {
                const f2* gb = lg + 4 * (GSTRIDE / 2);
                const bool sw = (p4 != 0);
                const f2 rrr  = sw ? gb[9]  : gb[0];
                const f2 rri  = sw ? gb[10] : gb[1];
                const f2 nrri = sw ? gb[11] : gb[2];
                const f2 rpr  = sw ? gb[6]  : gb[3];
                const f2 rpi  = sw ? gb[7]  : gb[4];
                const f2 nrpi = sw ? gb[8]  : gb[5];
                #pragma unroll
                for (int j = 0; j < 8; ++j) {
                    const f2 z = R[j], u = U[j];
                    const f2 pr = dpp2<0x4E>(z), pu = dpp2<0x4E>(u);
                    R[j] = __builtin_elementwise_fma(nrpi, pu, __builtin_elementwise_fma(rpr, pr, __builtin_elementwise_fma(nrri, u, rrr * z)));
                    U[j] = __builtin_elementwise_fma(rpr,  pu, __builtin_elementwise_fma(rpi, pr, __builtin_elementwise_fma(rrr,  u, rri * z)));
                }
            }
            {
                const f2* gb = lg + 5 * (GSTRIDE / 2);
                const bool sw = (p5 != 0);
                const f2 rrr  = sw ? gb[9]  : gb[0];
                const f2 rri  = sw ? gb[10] : gb[1];
                const f2 nrri = sw ? gb[11] : gb[2];
                const f2 rpr  = sw ? gb[6]  : gb[3];
                const f2 rpi  = sw ? gb[7]  : gb[4];
                const f2 nrpi = sw ? gb[8]  : gb[5];
                #pragma unroll
                for (int j = 0; j < 8; ++j) {
                    const f2 z = R[j], u = U[j];
                    const f2 pr = dpp2<0xB1>(z), pu = dpp2<0xB1>(u);
                    R[j] = __builtin_elementwise_fma(nrpi, pu, __builtin_elementwise_fma(rpr, pr, __builtin_elementwise_fma(nrri, u, rrr * z)));
                    U[j] = __builtin_elementwise_fma(rpr,  pu, __builtin_elementwise_fma(rpi, pr, __builtin_elementwise_fma(rrr,  u, rri * z)));
                }
            }
        }
        const int base = 16 * p4 + 32 * p5;
        #pragma unroll
        for (int j = 0; j < 8; ++j) {
            *(h2v*)(UhreT + bt*UPITCH + base + 2*j) =
                __builtin_amdgcn_cvt_pkrtz(R[j].x, R[j].y);
            *(h2v*)(UhimT + bt*UPITCH + base + 2*j) =
                __builtin_amdgcn_cvt_pkrtz(U[j].x, U[j].y);
        }
    }
    __syncthreads();

    {
        const int r32 = lane & 31, khp = lane >> 5;
        for (int i = wid; i < 16; i += 4) {
            const int T = i >> 2, s = i & 3;
            const int row = 32*T + r32, n = row >> 1, c = row & 1;
            const __fp16* src = c ? UhimT : UhreT;
            h8v v;
            #pragma unroll
            for (int e = 0; e < 8; ++e)
                v[e] = src[(khp*8 + 16*s + e) * UPITCH + n];
            *(h8v*)(wfrag + i*512 + lane*8) = v;
        }
        if (wid == 1) {
            const int rlow = lane & 15, kg = lane >> 4;
            float cw[6];
            #pragma unroll
            for (int q = 0; q < 6; ++q) cw[q] = post_w1[q*16 + rlow];
            for (int f = 0; f < 2; ++f) {
                h8v v;
                #pragma unroll
                for (int e = 0; e < 8; ++e) {
                    const int k2 = kg*8 + e + 32*f;
                    float sacc = 0.f;
                    #pragma unroll
                    for (int q = 0; q < 6; ++q)
                        sacc += ((k2 >> q) & 1) ? -cw[q] : cw[q];
                    v[e] = (__fp16)sacc;
                }
                *(h8v*)(wfrag + 8192 + f*512 + lane*8) = v;
            }
        }
    }
}

// ===========================================================================
// MAIN — verified R14 (22.28 us, absmax 1.953e-3). 4 waves/block, 64
// samples/wave in two 32-sample groups; GEMM1 = rolled-T 32x32x16 MFMA
// (one live acc, inline A-frag loads, VGPR<=128); GEMM2 = 16x16x32.
// ===========================================================================
__global__ __launch_bounds__(256) void qnn_mfma_kernel(
    const float* __restrict__ x,
    const float* __restrict__ pre_w1, const float* __restrict__ pre_b1,
    const float* __restrict__ pre_w2, const float* __restrict__ pre_b2,
    const __fp16* __restrict__ wfrag,
    const float* __restrict__ post_b1, const float* __restrict__ post_w2,
    const float* __restrict__ post_b2,
    float* __restrict__ out)
{
    __shared__ __align__(16) __fp16 ps[4][2048];
    const int tid  = threadIdx.x;
    const int lane = tid & 63, wid = tid >> 6;
    const int sbase = (blockIdx.x * 4 + wid) * 64;

    const h8v a2f0 = *(const h8v*)(wfrag + 8192 + lane*8);
    const h8v a2f1 = *(const h8v*)(wfrag + 8192 + 512 + lane*8);

    const float4 xv = ((const float4*)x)[sbase + lane];
    float h[16];
    #pragma unroll
    for (int j = 0; j < 16; ++j) {
        float a = pre_b1[j];
        a = fmaf(xv.x, pre_w1[0*16+j], a);
        a = fmaf(xv.y, pre_w1[1*16+j], a);
        a = fmaf(xv.z, pre_w1[2*16+j], a);
        a = fmaf(xv.w, pre_w1[3*16+j], a);
        h[j] = fmaxf(a, 0.f);
    }
    float fc[NQ], fs[NQ];
    #pragma unroll
    for (int q = 0; q < NQ; ++q) {
        float a = pre_b2[q];
        #pragma unroll
        for (int j = 0; j < 16; ++j) a = fmaf(h[j], pre_w2[j*NQ+q], a);
        const float y = 0.5f * tanh_fast(a) + 0.78539816339744831f;
        fc[q] = __cosf(y); fs[q] = __sinf(y);
    }
    const float b2x = post_b2[0], b2y = post_b2[1];
    const float b2z = post_b2[2], b2w = post_b2[3];

    const int sl32 = lane & 31, kh = lane >> 5;
    const int sl16 = lane & 15, g2 = lane >> 4;
    __fp16* myp = ps[wid];
    const int wswz = (sl32 & 7) << 4;

    #pragma unroll
    for (int G2 = 0; G2 < 2; ++G2) {
        const int srcb = (G2 * 32 + sl32) << 2;
        #define BP(v) __int_as_float(__builtin_amdgcn_ds_bpermute(srcb, __float_as_int(v)))
        const float q0c=BP(fc[0]), q0s=BP(fs[0]);
        const float q1c=BP(fc[1]), q1s=BP(fs[1]);
        const float q2c=BP(fc[2]), q2s=BP(fs[2]);
        const float q3c=BP(fc[3]), q3s=BP(fs[3]);
        const float q4c=BP(fc[4]), q4s=BP(fs[4]);
        const float q5c=BP(fc[5]), q5s=BP(fs[5]);
        #undef BP
        const float f3v = kh ? q3s : q3c;
        float t01[4], b8[8];
        t01[0] = q0c*q1c; t01[1] = q0s*q1c; t01[2] = q0c*q1s; t01[3] = q0s*q1s;
        #pragma unroll
        for (int e = 0; e < 8; ++e) b8[e] = t01[e & 3] * ((e & 4) ? q2s : q2c);
        h8v bs[4];
        #pragma unroll
        for (int s = 0; s < 4; ++s) {
            const float pre = f3v * ((s & 1) ? q4s : q4c) * ((s & 2) ? q5s : q5c);
            #pragma unroll
            for (int e2 = 0; e2 < 4; ++e2) {
                const h2v t = __builtin_amdgcn_cvt_pkrtz(b8[2*e2]*pre, b8[2*e2+1]*pre);
                bs[s][2*e2] = t[0]; bs[s][2*e2+1] = t[1];
            }
        }

        // GEMM1, rolled over T: one live accumulator, inline A-frag loads
        #pragma unroll 1
        for (int T = 0; T < 4; ++T) {
            f16f acc = (f16f)(0.f);
            #pragma unroll
            for (int s = 0; s < 4; ++s) {
                const h8v a = *(const h8v*)(wfrag + (T*4 + s)*512 + lane*8);
                acc = __builtin_amdgcn_mfma_f32_32x32x16_f16(a, bs[s], acc, 0, 0, 0);
            }
            #pragma unroll
            for (int a = 0; a < 4; ++a) {
                const float p0 = fmaf(acc[4*a+0], acc[4*a+0], acc[4*a+1] * acc[4*a+1]);
                const float p1 = fmaf(acc[4*a+2], acc[4*a+2], acc[4*a+3] * acc[4*a+3]);
                const h2v ph = __builtin_amdgcn_cvt_pkrtz(p0, p1);
                const int boff = (32*T + 8*a + 4*kh) ^ wswz;
                *(h2v*)((char*)myp + sl32*128 + boff) = ph;
            }
        }

        #pragma unroll
        for (int H = 0; H < 2; ++H) {
            const int smp  = H*16 + sl16;
            const int rswz = (smp & 7) << 4;
            const h8v pb0 = *(const h8v*)((const char*)myp + smp*128 + ((16*g2     ) ^ rswz));
            const h8v pb1 = *(const h8v*)((const char*)myp + smp*128 + ((16*g2 + 64) ^ rswz));
            f4v c2 = {0.f, 0.f, 0.f, 0.f};
            c2 = __builtin_amdgcn_mfma_f32_16x16x32_f16(a2f0, pb0, c2, 0, 0, 0);
            c2 = __builtin_amdgcn_mfma_f32_16x16x32_f16(a2f1, pb1, c2, 0, 0, 0);

            const float4 b1v = ((const float4*)post_b1)[g2];
            const float e0  = fmaxf(c2.x + b1v.x, 0.f);
            const float e1  = fmaxf(c2.y + b1v.y, 0.f);
            const float e2_ = fmaxf(c2.z + b1v.z, 0.f);
            const float e3  = fmaxf(c2.w + b1v.w, 0.f);
            const float4 w0 = ((const float4*)post_w2)[4*g2 + 0];
            const float4 w1 = ((const float4*)post_w2)[4*g2 + 1];
            const float4 w2 = ((const float4*)post_w2)[4*g2 + 2];
            const float4 w3 = ((const float4*)post_w2)[4*g2 + 3];
            float ox = fmaf(e0, w0.x, fmaf(e1, w1.x, fmaf(e2_, w2.x, e3 * w3.x)));
            float oy = fmaf(e0, w0.y, fmaf(e1, w1.y, fmaf(e2_, w2.y, e3 * w3.y)));
            float oz = fmaf(e0, w0.z, fmaf(e1, w1.z, fmaf(e2_, w2.z, e3 * w3.z)));
            float ow = fmaf(e0, w0.w, fmaf(e1, w1.w, fmaf(e2_, w2.w, e3 * w3.w)));
            ox += __shfl_xor(ox, 16, 64); ox += __shfl_xor(ox, 32, 64);
            oy += __shfl_xor(oy, 16, 64); oy += __shfl_xor(oy, 32, 64);
            oz += __shfl_xor(oz, 16, 64); oz += __shfl_xor(oz, 32, 64);
            ow += __shfl_xor(ow, 16, 64); ow += __shfl_xor(ow, 32, 64);
            if (lane < 16) {
                float4 r;
                r.x = ox + b2x; r.y = oy + b2y; r.z = oz + b2z; r.w = ow + b2w;
                ((float4*)out)[sbase + G2*32 + H*16 + sl16] = r;
            }
        }
    }
}

extern "C" void kernel_launch(void* const* d_in, const int* in_sizes, int n_in,
                              void* d_out, int out_size, void* d_ws, size_t ws_size,
                              hipStream_t stream) {
    const float* x       = (const float*)d_in[0];
    const float* pre_w1  = (const float*)d_in[1];
    const float* pre_b1  = (const float*)d_in[2];
    const float* pre_w2  = (const float*)d_in[3];
    const float* pre_b2  = (const float*)d_in[4];
    const float* qw      = (const float*)d_in[5];
    const float* post_w1 = (const float*)d_in[6];
    const float* post_b1 = (const float*)d_in[7];
    const float* post_w2 = (const float*)d_in[8];
    const float* post_b2 = (const float*)d_in[9];
    float* out = (float*)d_out;
    __fp16* wfrag = (__fp16*)d_ws;   // 18 KB of fragment weights

    prep_kernel<<<1, 256, 0, stream>>>(qw, post_w1, wfrag);
    qnn_mfma_kernel<<<QBATCH / 256, 256, 0, stream>>>(
        x, pre_w1, pre_b1, pre_w2, pre_b2, wfrag,
        post_b1, post_w2, post_b2, out);
}